// Round 9
// baseline (174.123 us; speedup 1.0000x reference)
//
#include <hip/hip_runtime.h>
#include <hip/hip_bf16.h>

// Problem constants
#define Hh 768
#define Ff 384      // H/2
#define Ee 9
#define Rr 10
#define Bb 8
#define Ss 4096
#define Nn_ENT 64
#define Pp 2016     // N*(N-1)/2
#define CH 16       // chunk size for seq prefix
#define NC 256      // S/CH

typedef short bf16x8 __attribute__((ext_vector_type(8)));
typedef float f32x4 __attribute__((ext_vector_type(4)));

// async global->LDS, 16B per lane. LDS dest is wave-uniform base + lane*16.
__device__ __forceinline__ void async_copy16(void* lds, const void* g) {
  auto* l = (__attribute__((address_space(3))) unsigned int*)(lds);
  auto* p = (const __attribute__((address_space(1))) unsigned int*)(g);
  __builtin_amdgcn_global_load_lds(p, l, 16, 0, 0);
}

// ---------------------------------------------------------------------------
// w1 (768x384 f32, k-major) -> Wt (384x768 bf16) via LDS tile transpose
// ---------------------------------------------------------------------------
__global__ __launch_bounds__(256) void transpose_w1(const float* __restrict__ w1,
                                                    unsigned short* __restrict__ wt) {
  __shared__ unsigned short tile[64][65];
  const int bk = blockIdx.x * 64;   // k block (12)
  const int bc = blockIdx.y * 64;   // col block (6)
  const int c = threadIdx.x & 63, kq = threadIdx.x >> 6;
#pragma unroll
  for (int i = 0; i < 16; ++i) {
    int k = kq * 16 + i;
    float v = w1[(size_t)(bk + k) * Ff + bc + c];
    tile[c][k] = __bfloat16_as_ushort(__float2bfloat16(v));
  }
  __syncthreads();
  const int k2 = threadIdx.x & 63, cq = threadIdx.x >> 6;
#pragma unroll
  for (int i = 0; i < 16; ++i) {
    int c2 = cq * 16 + i;
    wt[(size_t)(bc + c2) * Hh + bk + k2] = tile[c2][k2];
  }
}

// ---------------------------------------------------------------------------
// seq_prep: one streaming pass over seq -> seq16 (bf16) + chunk sums Pc.
// ---------------------------------------------------------------------------
__global__ __launch_bounds__(192) void seq_prep(const float* __restrict__ seq,
                                                unsigned short* __restrict__ seq16,
                                                float* __restrict__ Pc) {
  const int c = blockIdx.x, b = blockIdx.y;
  const int t = threadIdx.x;
  const size_t base = ((size_t)b * Ss + (size_t)c * CH) * Hh;
  const float4* p = (const float4*)(seq + base) + t;
  ushort4* q = (ushort4*)(seq16 + base) + t;
  float4 acc = {0.f, 0.f, 0.f, 0.f};
#pragma unroll
  for (int s = 0; s < CH; ++s) {
    float4 v = p[(size_t)s * (Hh / 4)];
    acc.x += v.x; acc.y += v.y; acc.z += v.z; acc.w += v.w;
    ushort4 o;
    o.x = __bfloat16_as_ushort(__float2bfloat16(v.x));
    o.y = __bfloat16_as_ushort(__float2bfloat16(v.y));
    o.z = __bfloat16_as_ushort(__float2bfloat16(v.z));
    o.w = __bfloat16_as_ushort(__float2bfloat16(v.w));
    q[(size_t)s * (Hh / 4)] = o;
  }
  ((float4*)(Pc + ((size_t)b * NC + c) * Hh))[t] = acc;
}

// ---------------------------------------------------------------------------
// GEMM1+GEMM2 fused: elog = relu(seq16 @ Wt^T + b1) @ w2 + b2.
// BM=64 x BN=384 (full width), BK=32, 512 threads / 8 waves (2m x 4n).
// T3-min DOUBLE-BUFFERED issue-ahead pipeline: STAGE(next) is issued BEFORE
// the current tile's ds_read+MFMA, so the vmcnt(0) drain at the barrier
// happens after a full compute phase (load latency hidden). LDS swizzle via
// pre-swizzled global source granule (lane&3)^(row&3), same XOR on read.
// LDS: 2x28KB A|B + 14KB w2 + b1 = 72.7KB -> 2 blocks/CU.
// ---------------------------------------------------------------------------
__global__ __launch_bounds__(512, 4) void gemm1_fused(const unsigned short* __restrict__ A,
                                                      const unsigned short* __restrict__ Wt,
                                                      const float* __restrict__ b1,
                                                      const float* __restrict__ w2,
                                                      const float* __restrict__ b2,
                                                      float* __restrict__ elog) {
  __shared__ unsigned short AB[2][448 * 32];       // per buf: A(64x32) | B(384x32)
  __shared__ float w2s[Ff * Ee];                   // 13824 B
  __shared__ float b1s[Ff];                        // 1536 B
  __shared__ float b2s[Ee];
  float* red = (float*)&AB[0][0];                  // epilogue alias (9216 B)

  const int t = threadIdx.x;
  const int wid = t >> 6, lane = t & 63;
  const int wm = wid >> 2, wn = wid & 3;
  const int fr = lane & 15, fq = lane >> 4;
  const int row0 = blockIdx.x * 64;

  // cache params in LDS
  for (int i = t; i < Ff * Ee; i += 512) w2s[i] = w2[i];
  for (int i = t; i < Ff; i += 512) b1s[i] = b1[i];
  if (t < Ee) b2s[t] = b2[t];

  // staging sources, pre-swizzled: LDS[row][slot] <- global granule slot^(row&3)
  const int lrow = lane >> 2;                          // local row 0..15
  const int sgr = (lane & 3) ^ (lrow & 3);             // source granule
  const unsigned short* aApt = A + (size_t)(row0 + wid * 16 + lrow) * Hh + sgr * 8; // waves 0-3
  const unsigned short* aB0 = Wt + (size_t)((wid * 3 + 0) * 16 + lrow) * Hh + sgr * 8;
  const unsigned short* aB1 = Wt + (size_t)((wid * 3 + 1) * 16 + lrow) * Hh + sgr * 8;
  const unsigned short* aB2 = Wt + (size_t)((wid * 3 + 2) * 16 + lrow) * Hh + sgr * 8;

#define STAGE(buf, ks) do {                                                  \
    const int k0s = (ks) * 32;                                               \
    if (wid < 4) async_copy16(&AB[buf][wid * 512], aApt + k0s);              \
    async_copy16(&AB[buf][2048 + (wid * 3 + 0) * 512], aB0 + k0s);           \
    async_copy16(&AB[buf][2048 + (wid * 3 + 1) * 512], aB1 + k0s);           \
    async_copy16(&AB[buf][2048 + (wid * 3 + 2) * 512], aB2 + k0s);           \
  } while (0)

  f32x4 acc[2][6] = {};

  STAGE(0, 0);
  __syncthreads();   // drain prologue loads

  int cur = 0;
  for (int ks = 0; ks < Hh / 32; ++ks) {
    const bool more = ks < (Hh / 32) - 1;
    if (more) STAGE(cur ^ 1, ks + 1);   // loads fly under this tile's compute
    const unsigned short* AsC = &AB[cur][0];
    const unsigned short* BsC = &AB[cur][2048];
    const int g2 = (fq ^ (fr & 3)) * 8;
    bf16x8 af[2], bfr[6];
#pragma unroll
    for (int m = 0; m < 2; ++m)
      af[m] = *(const bf16x8*)&AsC[(wm * 32 + m * 16 + fr) * 32 + g2];
#pragma unroll
    for (int n = 0; n < 6; ++n)
      bfr[n] = *(const bf16x8*)&BsC[(wn * 96 + n * 16 + fr) * 32 + g2];
#pragma unroll
    for (int m = 0; m < 2; ++m)
#pragma unroll
      for (int n = 0; n < 6; ++n)
        acc[m][n] = __builtin_amdgcn_mfma_f32_16x16x32_bf16(af[m], bfr[n], acc[m][n], 0, 0, 0);
    if (more) {
      __syncthreads();   // drains next-tile loads (already ~complete) + read fence
      cur ^= 1;
    }
  }
#undef STAGE
  __syncthreads();   // all AB reads done before red alias writes (race fix)

  // ---- fused entity-logits epilogue (h in registers) ----
#pragma unroll
  for (int m = 0; m < 2; ++m) {
#pragma unroll
    for (int j = 0; j < 4; ++j) {
      float p[Ee];
#pragma unroll
      for (int e = 0; e < Ee; ++e) p[e] = 0.f;
#pragma unroll
      for (int n = 0; n < 6; ++n) {
        const int col = wn * 96 + n * 16 + fr;
        const float hv = fmaxf(acc[m][n][j] + b1s[col], 0.f);
        const float* wrow = &w2s[col * Ee];
#pragma unroll
        for (int e = 0; e < Ee; ++e) p[e] = fmaf(hv, wrow[e], p[e]);
      }
#pragma unroll
      for (int mask = 1; mask <= 8; mask <<= 1)
#pragma unroll
        for (int e = 0; e < Ee; ++e) p[e] += __shfl_xor(p[e], mask);
      if (fr < Ee) {
        const int row = wm * 32 + m * 16 + fq * 4 + j;
        red[(wn * 64 + row) * Ee + fr] = p[fr];
      }
    }
  }
  __syncthreads();
  for (int idx = t; idx < 64 * Ee; idx += 512) {
    const int row = idx / Ee, e = idx - row * Ee;
    float v = red[(0 * 64 + row) * Ee + e] + red[(1 * 64 + row) * Ee + e]
            + red[(2 * 64 + row) * Ee + e] + red[(3 * 64 + row) * Ee + e] + b2s[e];
    elog[(size_t)(row0 + row) * Ee + e] = v;
  }
}

// ---------------------------------------------------------------------------
// U/V projection, split-K f32: part[ks][uv] += reprs(512x768) @ rw1-half.
// ---------------------------------------------------------------------------
__global__ __launch_bounds__(256) void gemm_uv_splitk(const float* __restrict__ A,
                                                      const float* __restrict__ rw1,
                                                      float* __restrict__ part) {
  const int uv = blockIdx.z & 1, ks = blockIdx.z >> 1;
  const float* Wp = rw1 + (size_t)uv * Hh * Hh + (size_t)ks * 192 * Hh;
  __shared__ float Ast[16][68];
  __shared__ float Wst[16][68];
  const int t = threadIdx.x;
  const int row0 = blockIdx.x * 64, col0 = blockIdx.y * 64;
  const int tm = (t & 15) * 4, tn = (t >> 4) * 4;
  const int lr = t >> 2, lk = (t & 3) * 4;
  const int wk = t >> 4, wc = (t & 15) * 4;
  float acc[4][4] = {};
  const float* Arow = A + (size_t)(row0 + lr) * Hh + ks * 192 + lk;
  for (int k0 = 0; k0 < 192; k0 += 16) {
    float4 av = *(const float4*)(Arow + k0);
    Ast[lk + 0][lr] = av.x; Ast[lk + 1][lr] = av.y;
    Ast[lk + 2][lr] = av.z; Ast[lk + 3][lr] = av.w;
    *(float4*)&Wst[wk][wc] = *(const float4*)(Wp + (size_t)(k0 + wk) * Hh + col0 + wc);
    __syncthreads();
#pragma unroll
    for (int kk = 0; kk < 16; ++kk) {
      const float4 a = *(const float4*)&Ast[kk][tm];
      const float4 b = *(const float4*)&Wst[kk][tn];
      acc[0][0] = fmaf(a.x, b.x, acc[0][0]); acc[0][1] = fmaf(a.x, b.y, acc[0][1]);
      acc[0][2] = fmaf(a.x, b.z, acc[0][2]); acc[0][3] = fmaf(a.x, b.w, acc[0][3]);
      acc[1][0] = fmaf(a.y, b.x, acc[1][0]); acc[1][1] = fmaf(a.y, b.y, acc[1][1]);
      acc[1][2] = fmaf(a.y, b.z, acc[1][2]); acc[1][3] = fmaf(a.y, b.w, acc[1][3]);
      acc[2][0] = fmaf(a.z, b.x, acc[2][0]); acc[2][1] = fmaf(a.z, b.y, acc[2][1]);
      acc[2][2] = fmaf(a.z, b.z, acc[2][2]); acc[2][3] = fmaf(a.z, b.w, acc[2][3]);
      acc[3][0] = fmaf(a.w, b.x, acc[3][0]); acc[3][1] = fmaf(a.w, b.y, acc[3][1]);
      acc[3][2] = fmaf(a.w, b.z, acc[3][2]); acc[3][3] = fmaf(a.w, b.w, acc[3][3]);
    }
    __syncthreads();
  }
  float* out = part + ((size_t)ks * 2 + uv) * (512 * Hh);
#pragma unroll
  for (int i = 0; i < 4; ++i) {
    float4 o; o.x = acc[i][0]; o.y = acc[i][1]; o.z = acc[i][2]; o.w = acc[i][3];
    *(float4*)(out + (size_t)(row0 + tm + i) * Hh + col0 + tn) = o;
  }
}

// UV[i] = sum of 4 K-split partials
__global__ __launch_bounds__(256) void uv_reduce(const float* __restrict__ part,
                                                 float* __restrict__ uv) {
  const int i = blockIdx.x * 256 + threadIdx.x;   // float4 idx, 196608 total
  const float4* p = (const float4*)part;
  float4 a = p[i], b = p[i + 196608], c = p[i + 2 * 196608], d = p[i + 3 * 196608];
  float4 o;
  o.x = (a.x + b.x) + (c.x + d.x);
  o.y = (a.y + b.y) + (c.y + d.y);
  o.z = (a.z + b.z) + (c.z + d.z);
  o.w = (a.w + b.w) + (c.w + d.w);
  ((float4*)uv)[i] = o;
}

// ---------------------------------------------------------------------------
// In-place inclusive scan of Pc along c, per (b,h). Block = (b, 64 h-values).
// ---------------------------------------------------------------------------
__global__ __launch_bounds__(256) void chunk_scan(float* __restrict__ Pc) {
  __shared__ float tile[NC][64];
  const int b = blockIdx.y;
  const int h0 = blockIdx.x * 64;
  float* base = Pc + (size_t)b * NC * Hh + h0;
  const int l = threadIdx.x & 63, g = threadIdx.x >> 6;
#pragma unroll 4
  for (int c = g * 64; c < g * 64 + 64; ++c)
    tile[c][l] = base[(size_t)c * Hh + l];
  __syncthreads();
  float run = 0.f;
#pragma unroll 4
  for (int c = g * 64; c < g * 64 + 64; ++c) {
    run += tile[c][l];
    tile[c][l] = run;
  }
  __syncthreads();
  float off = 0.f;
#pragma unroll
  for (int gg = 0; gg < 3; ++gg)
    if (gg < g) off += tile[gg * 64 + 63][l];
  __syncthreads();
  if (g > 0) {
#pragma unroll 4
    for (int c = g * 64; c < g * 64 + 64; ++c)
      tile[c][l] += off;
  }
  __syncthreads();
#pragma unroll 4
  for (int c = g * 64; c < g * 64 + 64; ++c)
    base[(size_t)c * Hh + l] = tile[c][l];
}

// ---------------------------------------------------------------------------
// entity_reprs: O(1) chunk-range via inclusive prefix + <=30 edge rows.
// ---------------------------------------------------------------------------
__global__ __launch_bounds__(192) void entity_reprs_k(const float* __restrict__ seq,
                                                      const float* __restrict__ Pc,
                                                      const int* __restrict__ spans,
                                                      float* __restrict__ reprs) {
  const int bn = blockIdx.x;
  const int b = bn >> 6;
  const int start = spans[bn * 2], end = spans[bn * 2 + 1];
  const int cnt = max(end - start, 1);
  const float inv = 1.0f / (float)cnt;
  const int cs = (start + CH - 1) >> 4, ce = end >> 4;
  const float* seqb = seq + (size_t)b * Ss * Hh;
  const float4* Pcb = (const float4*)(Pc + (size_t)b * NC * Hh);
  const int t = threadIdx.x;  // 192 x float4 = 768
  float4 acc = {0.f, 0.f, 0.f, 0.f};
  if (cs <= ce) {
    if (cs < ce) {
      float4 hi = Pcb[(size_t)(ce - 1) * 192 + t];
      acc.x += hi.x; acc.y += hi.y; acc.z += hi.z; acc.w += hi.w;
      if (cs > 0) {
        float4 lo = Pcb[(size_t)(cs - 1) * 192 + t];
        acc.x -= lo.x; acc.y -= lo.y; acc.z -= lo.z; acc.w -= lo.w;
      }
    }
    for (int s = start; s < cs * CH; ++s) {
      float4 v = ((const float4*)(seqb + (size_t)s * Hh))[t];
      acc.x += v.x; acc.y += v.y; acc.z += v.z; acc.w += v.w;
    }
    for (int s = ce * CH; s < end; ++s) {
      float4 v = ((const float4*)(seqb + (size_t)s * Hh))[t];
      acc.x += v.x; acc.y += v.y; acc.z += v.z; acc.w += v.w;
    }
  } else {
    for (int s = start; s < end; ++s) {
      float4 v = ((const float4*)(seqb + (size_t)s * Hh))[t];
      acc.x += v.x; acc.y += v.y; acc.z += v.z; acc.w += v.w;
    }
  }
  float4 o; o.x = acc.x * inv; o.y = acc.y * inv; o.z = acc.z * inv; o.w = acc.w * inv;
  ((float4*)(reprs + (size_t)bn * Hh))[t] = o;
}

// ---------------------------------------------------------------------------
// pooled argmax: one block per entity (512 blocks, 4 waves).
// ---------------------------------------------------------------------------
__global__ __launch_bounds__(256) void pooled_argmax(const float* __restrict__ elog,
                                                     const int* __restrict__ spans,
                                                     float* __restrict__ etypes) {
  __shared__ float red[4][Ee];
  const int bn = blockIdx.x;
  const int b = bn >> 6;
  const int start = spans[bn * 2], end = spans[bn * 2 + 1];
  const int t = threadIdx.x, lane = t & 63, w = t >> 6;
  float acc[Ee];
#pragma unroll
  for (int e = 0; e < Ee; ++e) acc[e] = 0.f;
  const float* p = elog + (size_t)b * Ss * Ee;
  for (int s = start + t; s < end; s += 256) {
    const float* q = p + (size_t)s * Ee;
#pragma unroll
    for (int e = 0; e < Ee; ++e) acc[e] += q[e];
  }
#pragma unroll
  for (int off = 32; off; off >>= 1)
#pragma unroll
    for (int e = 0; e < Ee; ++e) acc[e] += __shfl_down(acc[e], off);
  if (lane == 0) {
#pragma unroll
    for (int e = 0; e < Ee; ++e) red[w][e] = acc[e];
  }
  __syncthreads();
  if (t == 0) {
    int best = 0; float bv = -1e30f;
#pragma unroll
    for (int e = 0; e < Ee; ++e) {
      float v = red[0][e] + red[1][e] + red[2][e] + red[3][e];
      if (v > bv) { bv = v; best = e; }
    }
    etypes[bn] = (float)best;
  }
}

// ---------------------------------------------------------------------------
// relations: one wave per (b,p). rw2 + rb1 cached in LDS (stride-11 pad).
// ---------------------------------------------------------------------------
__global__ __launch_bounds__(256) void relations_k(const float* __restrict__ UV,
                                                   const float* __restrict__ rb1,
                                                   const float* __restrict__ rw2,
                                                   const float* __restrict__ rb2,
                                                   float* __restrict__ rlogits,
                                                   float* __restrict__ rtypes) {
  __shared__ float w2l[Hh * 11];   // 33792 B, [k*11 + r]
  __shared__ float b1l[Hh];        //  3072 B
  const int t = threadIdx.x;
  for (int i = t; i < Hh * Rr; i += 256) {
    const int k = i / Rr, r = i - k * Rr;
    w2l[k * 11 + r] = rw2[i];
  }
  for (int i = t; i < Hh; i += 256) b1l[i] = rb1[i];
  __syncthreads();

  const int p = blockIdx.x * 4 + (t >> 6);
  const int lane = t & 63;
  const int b = p / Pp, pp = p % Pp;
  int i = 0, off = 0;
  while (off + (Nn_ENT - 1 - i) <= pp) { off += Nn_ENT - 1 - i; ++i; }
  const int j = i + 1 + (pp - off);
  const float* u = UV + ((size_t)b * Nn_ENT + i) * Hh;
  const float* v = UV + (size_t)512 * Hh + ((size_t)b * Nn_ENT + j) * Hh;
  float acc[Rr];
#pragma unroll
  for (int r = 0; r < Rr; ++r) acc[r] = 0.f;
  for (int k = lane; k < Hh; k += 64) {
    float x = fmaxf(u[k] + v[k] + b1l[k], 0.f);
    const float* w = &w2l[k * 11];
#pragma unroll
    for (int r = 0; r < Rr; ++r) acc[r] = fmaf(x, w[r], acc[r]);
  }
#pragma unroll
  for (int off2 = 32; off2; off2 >>= 1)
#pragma unroll
    for (int r = 0; r < Rr; ++r) acc[r] += __shfl_down(acc[r], off2);
  if (lane == 0) {
    int best = 0; float bv = acc[0] + rb2[0];
    rlogits[(size_t)p * Rr + 0] = bv;
#pragma unroll
    for (int r = 1; r < Rr; ++r) {
      float val = acc[r] + rb2[r];
      rlogits[(size_t)p * Rr + r] = val;
      if (val > bv) { bv = val; best = r; }
    }
    rtypes[p] = (float)best;
  }
}

// ---------------------------------------------------------------------------
extern "C" void kernel_launch(void* const* d_in, const int* in_sizes, int n_in,
                              void* d_out, int out_size, void* d_ws, size_t ws_size,
                              hipStream_t stream) {
  const float* seq   = (const float*)d_in[0];
  const int*   spans = (const int*)d_in[2];
  const float* w1    = (const float*)d_in[3];
  const float* b1    = (const float*)d_in[4];
  const float* w2    = (const float*)d_in[5];
  const float* b2    = (const float*)d_in[6];
  const float* rw1   = (const float*)d_in[7];
  const float* rb1   = (const float*)d_in[8];
  const float* rw2   = (const float*)d_in[9];
  const float* rb2   = (const float*)d_in[10];

  float* out_elog = (float*)d_out;               // (B,S,E)   294912
  float* out_rlog = out_elog + 294912;           // (B,P,R)   161280
  float* out_repr = out_rlog + 161280;           // (B,N,H)   393216
  float* out_etyp = out_repr + 393216;           // (B,N)     512
  float* out_rtyp = out_etyp + 512;              // (B,P)     16128

  // workspace layout (bytes):
  unsigned short* ws_s16 = (unsigned short*)d_ws;                         // 50331648
  float*          ws_pc  = (float*)((char*)d_ws + 50331648);              //  6291456
  float*          ws_uv  = (float*)((char*)d_ws + 56623104);              //  3145728
  unsigned short* ws_wt  = (unsigned short*)((char*)d_ws + 59768832);     //   589824
  float*          ws_uvp = (float*)((char*)d_ws + 60358656);              // 12582912

  // 0) w1 -> bf16 transposed
  transpose_w1<<<dim3(12, 6), 256, 0, stream>>>(w1, ws_wt);
  // 1) seq -> bf16 + chunk sums (single streaming pass)
  seq_prep<<<dim3(NC, Bb), 192, 0, stream>>>(seq, ws_s16, ws_pc);
  // 2) elog = relu(seq16 @ w1 + b1) @ w2 + b2  (fused, dbuf issue-ahead)
  gemm1_fused<<<512, 512, 0, stream>>>(ws_s16, ws_wt, b1, w2, b2, out_elog);
  // 3) prefix scan of chunk sums
  chunk_scan<<<dim3(Hh / 64, Bb), 256, 0, stream>>>(ws_pc);
  // 4) entity_reprs (prefix diff + edge rows)
  entity_reprs_k<<<512, 192, 0, stream>>>(seq, ws_pc, spans, out_repr);
  // 5) U,V = reprs @ rw1 halves: split-K (4) + reduce
  gemm_uv_splitk<<<dim3(8, 12, 8), 256, 0, stream>>>(out_repr, rw1, ws_uvp);
  uv_reduce<<<768, 256, 0, stream>>>(ws_uvp, ws_uv);
  // 6) entity_types via pooled-logits argmax
  pooled_argmax<<<512, 256, 0, stream>>>(out_elog, spans, out_etyp);
  // 7) relation logits + types
  relations_k<<<4032, 256, 0, stream>>>(ws_uv, rb1, rw2, rb2, out_rlog, out_rtyp);
}

// Round 10
// 173.781 us; speedup vs baseline: 1.0020x; 1.0020x over previous
//
#include <hip/hip_runtime.h>
#include <hip/hip_bf16.h>

// Problem constants
#define Hh 768
#define Ff 384      // H/2
#define Ee 9
#define Rr 10
#define Bb 8
#define Ss 4096
#define Nn_ENT 64
#define Pp 2016     // N*(N-1)/2
#define CH 16       // chunk size for seq prefix
#define NC 256      // S/CH

typedef short bf16x8 __attribute__((ext_vector_type(8)));
typedef float f32x4 __attribute__((ext_vector_type(4)));

// async global->LDS, 16B per lane. LDS dest is wave-uniform base + lane*16.
__device__ __forceinline__ void async_copy16(void* lds, const void* g) {
  auto* l = (__attribute__((address_space(3))) unsigned int*)(lds);
  auto* p = (const __attribute__((address_space(1))) unsigned int*)(g);
  __builtin_amdgcn_global_load_lds(p, l, 16, 0, 0);
}

// ---------------------------------------------------------------------------
// w1 (768x384 f32, k-major) -> Wt (384x768 bf16) via LDS tile transpose
// ---------------------------------------------------------------------------
__global__ __launch_bounds__(256) void transpose_w1(const float* __restrict__ w1,
                                                    unsigned short* __restrict__ wt) {
  __shared__ unsigned short tile[64][65];
  const int bk = blockIdx.x * 64;   // k block (12)
  const int bc = blockIdx.y * 64;   // col block (6)
  const int c = threadIdx.x & 63, kq = threadIdx.x >> 6;
#pragma unroll
  for (int i = 0; i < 16; ++i) {
    int k = kq * 16 + i;
    float v = w1[(size_t)(bk + k) * Ff + bc + c];
    tile[c][k] = __bfloat16_as_ushort(__float2bfloat16(v));
  }
  __syncthreads();
  const int k2 = threadIdx.x & 63, cq = threadIdx.x >> 6;
#pragma unroll
  for (int i = 0; i < 16; ++i) {
    int c2 = cq * 16 + i;
    wt[(size_t)(bc + c2) * Hh + bk + k2] = tile[c2][k2];
  }
}

// ---------------------------------------------------------------------------
// seq_prep: one streaming pass over seq -> seq16 (bf16) + chunk sums Pc.
// ---------------------------------------------------------------------------
__global__ __launch_bounds__(192) void seq_prep(const float* __restrict__ seq,
                                                unsigned short* __restrict__ seq16,
                                                float* __restrict__ Pc) {
  const int c = blockIdx.x, b = blockIdx.y;
  const int t = threadIdx.x;
  const size_t base = ((size_t)b * Ss + (size_t)c * CH) * Hh;
  const float4* p = (const float4*)(seq + base) + t;
  ushort4* q = (ushort4*)(seq16 + base) + t;
  float4 acc = {0.f, 0.f, 0.f, 0.f};
#pragma unroll
  for (int s = 0; s < CH; ++s) {
    float4 v = p[(size_t)s * (Hh / 4)];
    acc.x += v.x; acc.y += v.y; acc.z += v.z; acc.w += v.w;
    ushort4 o;
    o.x = __bfloat16_as_ushort(__float2bfloat16(v.x));
    o.y = __bfloat16_as_ushort(__float2bfloat16(v.y));
    o.z = __bfloat16_as_ushort(__float2bfloat16(v.z));
    o.w = __bfloat16_as_ushort(__float2bfloat16(v.w));
    q[(size_t)s * (Hh / 4)] = o;
  }
  ((float4*)(Pc + ((size_t)b * NC + c) * Hh))[t] = acc;
}

// ---------------------------------------------------------------------------
// GEMM1+GEMM2 fused: elog = relu(seq16 @ Wt^T + b1) @ w2 + b2.
// BM=64 x BN=384 (full width), BK=32, 512 threads / 8 waves (2m x 4n).
// STATIC double-buffer (AB0/AB1 named arrays, x2-unrolled loop) so the
// compiler can prove in-flight gload_lds (next buf) doesn't alias the
// ds_reads (cur buf) -> no conservative vmcnt(0) before reads; loads fly
// under a full compute phase. Full-period swizzle: source granule
// (lane&3)^((row>>1)&3), read slot fq^((fr>>1)&3) -> conflict-free b128.
// ---------------------------------------------------------------------------
__global__ __launch_bounds__(512, 4) void gemm1_fused(const unsigned short* __restrict__ A,
                                                      const unsigned short* __restrict__ Wt,
                                                      const float* __restrict__ b1,
                                                      const float* __restrict__ w2,
                                                      const float* __restrict__ b2,
                                                      float* __restrict__ elog) {
  __shared__ unsigned short AB0[448 * 32];         // A(64x32) | B(384x32) = 28 KB
  __shared__ unsigned short AB1[448 * 32];         // 28 KB
  __shared__ float w2s[Ff * Ee];                   // 13824 B
  __shared__ float b1s[Ff];                        // 1536 B
  __shared__ float b2s[Ee];
  float* red = (float*)&AB0[0];                    // epilogue alias (9216 B)

  const int t = threadIdx.x;
  const int wid = t >> 6, lane = t & 63;
  const int wm = wid >> 2, wn = wid & 3;
  const int fr = lane & 15, fq = lane >> 4;
  const int row0 = blockIdx.x * 64;

  // cache params in LDS
  for (int i = t; i < Ff * Ee; i += 512) w2s[i] = w2[i];
  for (int i = t; i < Ff; i += 512) b1s[i] = b1[i];
  if (t < Ee) b2s[t] = b2[t];

  // staging sources, pre-swizzled: LDS[row][lane&3] <- global granule
  // (lane&3)^((row>>1)&3)  (full 8-row period over the 64B rows)
  const int lrow = lane >> 2;                          // local row 0..15
  const int sgr = (lane & 3) ^ ((lrow >> 1) & 3);      // source granule
  const unsigned short* aApt = A + (size_t)(row0 + wid * 16 + lrow) * Hh + sgr * 8; // waves 0-3
  const unsigned short* aB0 = Wt + (size_t)((wid * 3 + 0) * 16 + lrow) * Hh + sgr * 8;
  const unsigned short* aB1 = Wt + (size_t)((wid * 3 + 1) * 16 + lrow) * Hh + sgr * 8;
  const unsigned short* aB2 = Wt + (size_t)((wid * 3 + 2) * 16 + lrow) * Hh + sgr * 8;

#define STAGE(BUF, ks) do {                                                  \
    const int k0s = (ks) * 32;                                               \
    if (wid < 4) async_copy16(&BUF[wid * 512], aApt + k0s);                  \
    async_copy16(&BUF[2048 + (wid * 3 + 0) * 512], aB0 + k0s);               \
    async_copy16(&BUF[2048 + (wid * 3 + 1) * 512], aB1 + k0s);               \
    async_copy16(&BUF[2048 + (wid * 3 + 2) * 512], aB2 + k0s);               \
  } while (0)

#define COMPUTE(BUF) do {                                                    \
    const unsigned short* AsC = &BUF[0];                                     \
    const unsigned short* BsC = &BUF[2048];                                  \
    bf16x8 af[2], bfr[6];                                                    \
    _Pragma("unroll")                                                        \
    for (int m = 0; m < 2; ++m)                                              \
      af[m] = *(const bf16x8*)&AsC[(wm * 32 + m * 16 + fr) * 32 + g2];       \
    _Pragma("unroll")                                                        \
    for (int n = 0; n < 6; ++n)                                              \
      bfr[n] = *(const bf16x8*)&BsC[(wn * 96 + n * 16 + fr) * 32 + g2];      \
    _Pragma("unroll")                                                        \
    for (int m = 0; m < 2; ++m)                                              \
      _Pragma("unroll")                                                      \
      for (int n = 0; n < 6; ++n)                                            \
        acc[m][n] = __builtin_amdgcn_mfma_f32_16x16x32_bf16(af[m], bfr[n], acc[m][n], 0, 0, 0); \
  } while (0)

  f32x4 acc[2][6] = {};
  const int g2 = (fq ^ ((fr >> 1) & 3)) * 8;   // read slot (elements)

  STAGE(AB0, 0);
  __syncthreads();   // drain prologue loads

#pragma unroll 1
  for (int ks = 0; ks < Hh / 32; ks += 2) {      // 24 steps, 12 iterations
    if (ks + 1 < Hh / 32) STAGE(AB1, ks + 1);    // fly under COMPUTE(AB0)
    COMPUTE(AB0);
    __syncthreads();                             // AB1 ready; AB0 reads done
    if (ks + 2 < Hh / 32) STAGE(AB0, ks + 2);    // fly under COMPUTE(AB1)
    COMPUTE(AB1);
    __syncthreads();                             // AB0 ready; AB1 reads done
  }
#undef STAGE
#undef COMPUTE

  // ---- fused entity-logits epilogue (h in registers) ----
#pragma unroll
  for (int m = 0; m < 2; ++m) {
#pragma unroll
    for (int j = 0; j < 4; ++j) {
      float p[Ee];
#pragma unroll
      for (int e = 0; e < Ee; ++e) p[e] = 0.f;
#pragma unroll
      for (int n = 0; n < 6; ++n) {
        const int col = wn * 96 + n * 16 + fr;
        const float hv = fmaxf(acc[m][n][j] + b1s[col], 0.f);
        const float* wrow = &w2s[col * Ee];
#pragma unroll
        for (int e = 0; e < Ee; ++e) p[e] = fmaf(hv, wrow[e], p[e]);
      }
#pragma unroll
      for (int mask = 1; mask <= 8; mask <<= 1)
#pragma unroll
        for (int e = 0; e < Ee; ++e) p[e] += __shfl_xor(p[e], mask);
      if (fr < Ee) {
        const int row = wm * 32 + m * 16 + fq * 4 + j;
        red[(wn * 64 + row) * Ee + fr] = p[fr];
      }
    }
  }
  __syncthreads();
  for (int idx = t; idx < 64 * Ee; idx += 512) {
    const int row = idx / Ee, e = idx - row * Ee;
    float v = red[(0 * 64 + row) * Ee + e] + red[(1 * 64 + row) * Ee + e]
            + red[(2 * 64 + row) * Ee + e] + red[(3 * 64 + row) * Ee + e] + b2s[e];
    elog[(size_t)(row0 + row) * Ee + e] = v;
  }
}

// ---------------------------------------------------------------------------
// U/V projection, split-K f32: part[ks][uv] += reprs(512x768) @ rw1-half.
// ---------------------------------------------------------------------------
__global__ __launch_bounds__(256) void gemm_uv_splitk(const float* __restrict__ A,
                                                      const float* __restrict__ rw1,
                                                      float* __restrict__ part) {
  const int uv = blockIdx.z & 1, ks = blockIdx.z >> 1;
  const float* Wp = rw1 + (size_t)uv * Hh * Hh + (size_t)ks * 192 * Hh;
  __shared__ float Ast[16][68];
  __shared__ float Wst[16][68];
  const int t = threadIdx.x;
  const int row0 = blockIdx.x * 64, col0 = blockIdx.y * 64;
  const int tm = (t & 15) * 4, tn = (t >> 4) * 4;
  const int lr = t >> 2, lk = (t & 3) * 4;
  const int wk = t >> 4, wc = (t & 15) * 4;
  float acc[4][4] = {};
  const float* Arow = A + (size_t)(row0 + lr) * Hh + ks * 192 + lk;
  for (int k0 = 0; k0 < 192; k0 += 16) {
    float4 av = *(const float4*)(Arow + k0);
    Ast[lk + 0][lr] = av.x; Ast[lk + 1][lr] = av.y;
    Ast[lk + 2][lr] = av.z; Ast[lk + 3][lr] = av.w;
    *(float4*)&Wst[wk][wc] = *(const float4*)(Wp + (size_t)(k0 + wk) * Hh + col0 + wc);
    __syncthreads();
#pragma unroll
    for (int kk = 0; kk < 16; ++kk) {
      const float4 a = *(const float4*)&Ast[kk][tm];
      const float4 b = *(const float4*)&Wst[kk][tn];
      acc[0][0] = fmaf(a.x, b.x, acc[0][0]); acc[0][1] = fmaf(a.x, b.y, acc[0][1]);
      acc[0][2] = fmaf(a.x, b.z, acc[0][2]); acc[0][3] = fmaf(a.x, b.w, acc[0][3]);
      acc[1][0] = fmaf(a.y, b.x, acc[1][0]); acc[1][1] = fmaf(a.y, b.y, acc[1][1]);
      acc[1][2] = fmaf(a.y, b.z, acc[1][2]); acc[1][3] = fmaf(a.y, b.w, acc[1][3]);
      acc[2][0] = fmaf(a.z, b.x, acc[2][0]); acc[2][1] = fmaf(a.z, b.y, acc[2][1]);
      acc[2][2] = fmaf(a.z, b.z, acc[2][2]); acc[2][3] = fmaf(a.z, b.w, acc[2][3]);
      acc[3][0] = fmaf(a.w, b.x, acc[3][0]); acc[3][1] = fmaf(a.w, b.y, acc[3][1]);
      acc[3][2] = fmaf(a.w, b.z, acc[3][2]); acc[3][3] = fmaf(a.w, b.w, acc[3][3]);
    }
    __syncthreads();
  }
  float* out = part + ((size_t)ks * 2 + uv) * (512 * Hh);
#pragma unroll
  for (int i = 0; i < 4; ++i) {
    float4 o; o.x = acc[i][0]; o.y = acc[i][1]; o.z = acc[i][2]; o.w = acc[i][3];
    *(float4*)(out + (size_t)(row0 + tm + i) * Hh + col0 + tn) = o;
  }
}

// UV[i] = sum of 4 K-split partials
__global__ __launch_bounds__(256) void uv_reduce(const float* __restrict__ part,
                                                 float* __restrict__ uv) {
  const int i = blockIdx.x * 256 + threadIdx.x;   // float4 idx, 196608 total
  const float4* p = (const float4*)part;
  float4 a = p[i], b = p[i + 196608], c = p[i + 2 * 196608], d = p[i + 3 * 196608];
  float4 o;
  o.x = (a.x + b.x) + (c.x + d.x);
  o.y = (a.y + b.y) + (c.y + d.y);
  o.z = (a.z + b.z) + (c.z + d.z);
  o.w = (a.w + b.w) + (c.w + d.w);
  ((float4*)uv)[i] = o;
}

// ---------------------------------------------------------------------------
// In-place inclusive scan of Pc along c, per (b,h). Block = (b, 64 h-values).
// ---------------------------------------------------------------------------
__global__ __launch_bounds__(256) void chunk_scan(float* __restrict__ Pc) {
  __shared__ float tile[NC][64];
  const int b = blockIdx.y;
  const int h0 = blockIdx.x * 64;
  float* base = Pc + (size_t)b * NC * Hh + h0;
  const int l = threadIdx.x & 63, g = threadIdx.x >> 6;
#pragma unroll 4
  for (int c = g * 64; c < g * 64 + 64; ++c)
    tile[c][l] = base[(size_t)c * Hh + l];
  __syncthreads();
  float run = 0.f;
#pragma unroll 4
  for (int c = g * 64; c < g * 64 + 64; ++c) {
    run += tile[c][l];
    tile[c][l] = run;
  }
  __syncthreads();
  float off = 0.f;
#pragma unroll
  for (int gg = 0; gg < 3; ++gg)
    if (gg < g) off += tile[gg * 64 + 63][l];
  __syncthreads();
  if (g > 0) {
#pragma unroll 4
    for (int c = g * 64; c < g * 64 + 64; ++c)
      tile[c][l] += off;
  }
  __syncthreads();
#pragma unroll 4
  for (int c = g * 64; c < g * 64 + 64; ++c)
    base[(size_t)c * Hh + l] = tile[c][l];
}

// ---------------------------------------------------------------------------
// entity_reprs: O(1) chunk-range via inclusive prefix + <=30 edge rows.
// ---------------------------------------------------------------------------
__global__ __launch_bounds__(192) void entity_reprs_k(const float* __restrict__ seq,
                                                      const float* __restrict__ Pc,
                                                      const int* __restrict__ spans,
                                                      float* __restrict__ reprs) {
  const int bn = blockIdx.x;
  const int b = bn >> 6;
  const int start = spans[bn * 2], end = spans[bn * 2 + 1];
  const int cnt = max(end - start, 1);
  const float inv = 1.0f / (float)cnt;
  const int cs = (start + CH - 1) >> 4, ce = end >> 4;
  const float* seqb = seq + (size_t)b * Ss * Hh;
  const float4* Pcb = (const float4*)(Pc + (size_t)b * NC * Hh);
  const int t = threadIdx.x;  // 192 x float4 = 768
  float4 acc = {0.f, 0.f, 0.f, 0.f};
  if (cs <= ce) {
    if (cs < ce) {
      float4 hi = Pcb[(size_t)(ce - 1) * 192 + t];
      acc.x += hi.x; acc.y += hi.y; acc.z += hi.z; acc.w += hi.w;
      if (cs > 0) {
        float4 lo = Pcb[(size_t)(cs - 1) * 192 + t];
        acc.x -= lo.x; acc.y -= lo.y; acc.z -= lo.z; acc.w -= lo.w;
      }
    }
    for (int s = start; s < cs * CH; ++s) {
      float4 v = ((const float4*)(seqb + (size_t)s * Hh))[t];
      acc.x += v.x; acc.y += v.y; acc.z += v.z; acc.w += v.w;
    }
    for (int s = ce * CH; s < end; ++s) {
      float4 v = ((const float4*)(seqb + (size_t)s * Hh))[t];
      acc.x += v.x; acc.y += v.y; acc.z += v.z; acc.w += v.w;
    }
  } else {
    for (int s = start; s < end; ++s) {
      float4 v = ((const float4*)(seqb + (size_t)s * Hh))[t];
      acc.x += v.x; acc.y += v.y; acc.z += v.z; acc.w += v.w;
    }
  }
  float4 o; o.x = acc.x * inv; o.y = acc.y * inv; o.z = acc.z * inv; o.w = acc.w * inv;
  ((float4*)(reprs + (size_t)bn * Hh))[t] = o;
}

// ---------------------------------------------------------------------------
// pooled argmax: one block per entity (512 blocks, 4 waves).
// ---------------------------------------------------------------------------
__global__ __launch_bounds__(256) void pooled_argmax(const float* __restrict__ elog,
                                                     const int* __restrict__ spans,
                                                     float* __restrict__ etypes) {
  __shared__ float red[4][Ee];
  const int bn = blockIdx.x;
  const int b = bn >> 6;
  const int start = spans[bn * 2], end = spans[bn * 2 + 1];
  const int t = threadIdx.x, lane = t & 63, w = t >> 6;
  float acc[Ee];
#pragma unroll
  for (int e = 0; e < Ee; ++e) acc[e] = 0.f;
  const float* p = elog + (size_t)b * Ss * Ee;
  for (int s = start + t; s < end; s += 256) {
    const float* q = p + (size_t)s * Ee;
#pragma unroll
    for (int e = 0; e < Ee; ++e) acc[e] += q[e];
  }
#pragma unroll
  for (int off = 32; off; off >>= 1)
#pragma unroll
    for (int e = 0; e < Ee; ++e) acc[e] += __shfl_down(acc[e], off);
  if (lane == 0) {
#pragma unroll
    for (int e = 0; e < Ee; ++e) red[w][e] = acc[e];
  }
  __syncthreads();
  if (t == 0) {
    int best = 0; float bv = -1e30f;
#pragma unroll
    for (int e = 0; e < Ee; ++e) {
      float v = red[0][e] + red[1][e] + red[2][e] + red[3][e];
      if (v > bv) { bv = v; best = e; }
    }
    etypes[bn] = (float)best;
  }
}

// ---------------------------------------------------------------------------
// relations: one wave per (b,p). rw2 + rb1 cached in LDS (stride-11 pad).
// ---------------------------------------------------------------------------
__global__ __launch_bounds__(256) void relations_k(const float* __restrict__ UV,
                                                   const float* __restrict__ rb1,
                                                   const float* __restrict__ rw2,
                                                   const float* __restrict__ rb2,
                                                   float* __restrict__ rlogits,
                                                   float* __restrict__ rtypes) {
  __shared__ float w2l[Hh * 11];   // 33792 B, [k*11 + r]
  __shared__ float b1l[Hh];        //  3072 B
  const int t = threadIdx.x;
  for (int i = t; i < Hh * Rr; i += 256) {
    const int k = i / Rr, r = i - k * Rr;
    w2l[k * 11 + r] = rw2[i];
  }
  for (int i = t; i < Hh; i += 256) b1l[i] = rb1[i];
  __syncthreads();

  const int p = blockIdx.x * 4 + (t >> 6);
  const int lane = t & 63;
  const int b = p / Pp, pp = p % Pp;
  int i = 0, off = 0;
  while (off + (Nn_ENT - 1 - i) <= pp) { off += Nn_ENT - 1 - i; ++i; }
  const int j = i + 1 + (pp - off);
  const float* u = UV + ((size_t)b * Nn_ENT + i) * Hh;
  const float* v = UV + (size_t)512 * Hh + ((size_t)b * Nn_ENT + j) * Hh;
  float acc[Rr];
#pragma unroll
  for (int r = 0; r < Rr; ++r) acc[r] = 0.f;
  for (int k = lane; k < Hh; k += 64) {
    float x = fmaxf(u[k] + v[k] + b1l[k], 0.f);
    const float* w = &w2l[k * 11];
#pragma unroll
    for (int r = 0; r < Rr; ++r) acc[r] = fmaf(x, w[r], acc[r]);
  }
#pragma unroll
  for (int off2 = 32; off2; off2 >>= 1)
#pragma unroll
    for (int r = 0; r < Rr; ++r) acc[r] += __shfl_down(acc[r], off2);
  if (lane == 0) {
    int best = 0; float bv = acc[0] + rb2[0];
    rlogits[(size_t)p * Rr + 0] = bv;
#pragma unroll
    for (int r = 1; r < Rr; ++r) {
      float val = acc[r] + rb2[r];
      rlogits[(size_t)p * Rr + r] = val;
      if (val > bv) { bv = val; best = r; }
    }
    rtypes[p] = (float)best;
  }
}

// ---------------------------------------------------------------------------
extern "C" void kernel_launch(void* const* d_in, const int* in_sizes, int n_in,
                              void* d_out, int out_size, void* d_ws, size_t ws_size,
                              hipStream_t stream) {
  const float* seq   = (const float*)d_in[0];
  const int*   spans = (const int*)d_in[2];
  const float* w1    = (const float*)d_in[3];
  const float* b1    = (const float*)d_in[4];
  const float* w2    = (const float*)d_in[5];
  const float* b2    = (const float*)d_in[6];
  const float* rw1   = (const float*)d_in[7];
  const float* rb1   = (const float*)d_in[8];
  const float* rw2   = (const float*)d_in[9];
  const float* rb2   = (const float*)d_in[10];

  float* out_elog = (float*)d_out;               // (B,S,E)   294912
  float* out_rlog = out_elog + 294912;           // (B,P,R)   161280
  float* out_repr = out_rlog + 161280;           // (B,N,H)   393216
  float* out_etyp = out_repr + 393216;           // (B,N)     512
  float* out_rtyp = out_etyp + 512;              // (B,P)     16128

  // workspace layout (bytes):
  unsigned short* ws_s16 = (unsigned short*)d_ws;                         // 50331648
  float*          ws_pc  = (float*)((char*)d_ws + 50331648);              //  6291456
  float*          ws_uv  = (float*)((char*)d_ws + 56623104);              //  3145728
  unsigned short* ws_wt  = (unsigned short*)((char*)d_ws + 59768832);     //   589824
  float*          ws_uvp = (float*)((char*)d_ws + 60358656);              // 12582912

  // 0) w1 -> bf16 transposed
  transpose_w1<<<dim3(12, 6), 256, 0, stream>>>(w1, ws_wt);
  // 1) seq -> bf16 + chunk sums (single streaming pass)
  seq_prep<<<dim3(NC, Bb), 192, 0, stream>>>(seq, ws_s16, ws_pc);
  // 2) elog = relu(seq16 @ w1 + b1) @ w2 + b2  (fused, static dbuf pipeline)
  gemm1_fused<<<512, 512, 0, stream>>>(ws_s16, ws_wt, b1, w2, b2, out_elog);
  // 3) prefix scan of chunk sums
  chunk_scan<<<dim3(Hh / 64, Bb), 256, 0, stream>>>(ws_pc);
  // 4) entity_reprs (prefix diff + edge rows)
  entity_reprs_k<<<512, 192, 0, stream>>>(seq, ws_pc, spans, out_repr);
  // 5) U,V = reprs @ rw1 halves: split-K (4) + reduce
  gemm_uv_splitk<<<dim3(8, 12, 8), 256, 0, stream>>>(out_repr, rw1, ws_uvp);
  uv_reduce<<<768, 256, 0, stream>>>(ws_uvp, ws_uv);
  // 6) entity_types via pooled-logits argmax
  pooled_argmax<<<512, 256, 0, stream>>>(out_elog, spans, out_etyp);
  // 7) relation logits + types
  relations_k<<<4032, 256, 0, stream>>>(ws_uv, rb1, rw2, rb2, out_rlog, out_rtyp);
}